// Round 7
// baseline (214.675 us; speedup 1.0000x reference)
//
#include <hip/hip_runtime.h>
#include <hip/hip_bf16.h>

// VariableSelectionNetwork (TFT VSN) fused kernel for MI355X / gfx950.
// B=64 T=512 F=32 U=64, rows N = B*T = 32768.
// out = concat( out[N][64], w[N][32] ) in f32.
//
// R6: phase A (weights GRN) moved onto MFMA via the same transposed-chain /
// custom-k-order trick as phase B; computed redundantly per wave -> zero
// phase-A barriers. vect staging LDS removed: direct per-lane global loads
// (loop-affine addresses, 16-lane broadcast). 3 barriers per block total.

typedef float f4      __attribute__((ext_vector_type(4)));
typedef float f2      __attribute__((ext_vector_type(2)));
typedef float f32x4   __attribute__((ext_vector_type(4)));
typedef short bf16x8  __attribute__((ext_vector_type(8)));
typedef unsigned short u16x4 __attribute__((ext_vector_type(4)));
typedef unsigned short u16x8 __attribute__((ext_vector_type(8)));

#define N_ROWS 32768
#define F_DIM  32
#define U_DIM  64
#define RPB    16
#define NTHR   256
#define NBLK   (N_ROWS / RPB)   // 2048

// ws layout: wtg frags [3*32*512 + 512] bf16x8 ; vect at byte 794624
#define PHA_FRAG 49152          // frag index of phase-A weight frags
#define VECT_BYTE_OFF 794624

// ---- LDS layout (total 16384 B) ----
#define X_OFF   0        // f32[16][36] x tile                      (2304)
#define WT_OFF  2304     // u16[16][40] softmax weights bf16        (1280)
#define VA_OFF  3584     // f32[6][32]  phase-A bias vectors        (768)
                         // finale: cmb f32[4][1024] overlays everything
#define SMEM_BYTES 16384

__device__ __forceinline__ unsigned short bfu(float x) {
  union { __hip_bfloat16 h; unsigned short u; } c;
  c.h = __float2bfloat16(x);
  return c.u;
}
__device__ __forceinline__ float bf2f(unsigned short u) {
  union { float f; unsigned v; } c; c.v = ((unsigned)u) << 16; return c.f;
}

// =====================================================================
// prep:
//  m=0: W2 as A-frags for transposed GEMM1 (k = 8g+32kt+j)
//  m=1,2: Wg1/Wg2 as B-frags, custom k-order k = 4g+(j&3)+16(j>>2)+32kt
//  pha (frag 49152+): w1w^T A-frags (k=8lg+j) ; w2w/wg1w/wg2w^T A-frags
//       with custom k-order k = 4lg+(j&3)+16(j>>2)
//  vect[f][576] = [W1|b1|b2| Q:(bg1,bg2,Wp,bp)[u] | G:(gamma,beta)[u]]
// =====================================================================
__global__ __launch_bounds__(256) void vsn_prep(
    const float* __restrict__ W2,  const float* __restrict__ Wg1, const float* __restrict__ Wg2,
    const float* __restrict__ W1,  const float* __restrict__ b1,  const float* __restrict__ b2,
    const float* __restrict__ bg1, const float* __restrict__ bg2,
    const float* __restrict__ Wp,  const float* __restrict__ bp,
    const float* __restrict__ gamma_, const float* __restrict__ beta_,
    const float* __restrict__ w1w, const float* __restrict__ w2w,
    const float* __restrict__ wg1w, const float* __restrict__ wg2w,
    unsigned short* __restrict__ wtg, float* __restrict__ vect)
{
  const int t = threadIdx.x, blk = blockIdx.x;
  if (blk < 192) {
    const int m = blk >> 6;              // 0..2
    const int f = (blk >> 1) & 31;
    const int half = blk & 1;
    const float* src = (m == 0) ? W2 : (m == 1) ? Wg1 : Wg2;
    src += f * 4096;
    const int c  = half * 256 + t;       // chunk 0..511
    const int nt = c >> 7;
    const int rr = c & 127;
    const int kt = rr >> 6;
    const int ln = rr & 63;
    const int g  = ln >> 4, lrr = ln & 15;
    const int uo = lrr + 16 * nt;
    u16x8 tmp;
    if (m == 0) {
      #pragma unroll
      for (int j = 0; j < 8; ++j)
        tmp[j] = bfu(src[(8 * g + 32 * kt + j) * 64 + uo]);
    } else {
      #pragma unroll
      for (int j = 0; j < 8; ++j)
        tmp[j] = bfu(src[(4 * g + (j & 3) + 16 * (j >> 2) + 32 * kt) * 64 + uo]);
    }
    *(u16x8*)(wtg + ((size_t)(m * 32 + f) * 512 + c) * 8) = tmp;
  } else if (blk < 194) {
    const int h = blk - 192;             // 0..1
    for (int i = h * 1024 + t; i < (h + 1) * 1024; i += 256) {
      const int f = i >> 6, u = i & 63;
      float* vf = vect + f * 576;
      vf[u]              = W1[i];
      vf[64 + u]         = b1[i];
      vf[128 + u]        = b2[i];
      vf[192 + u * 4 + 0] = bg1[i];
      vf[192 + u * 4 + 1] = bg2[i];
      vf[192 + u * 4 + 2] = Wp[i];
      vf[192 + u * 4 + 3] = bp[i];
      vf[448 + u * 2 + 0] = gamma_[i];
      vf[448 + u * 2 + 1] = beta_[i];
    }
  } else {
    // phase-A weight frags: 512 frags
    #pragma unroll
    for (int cc = 0; cc < 2; ++cc) {
      const int q = t + cc * 256;        // 0..511
      const int mat = q >> 7;            // 0 w1w, 1 w2w, 2 wg1w, 3 wg2w
      const int nt  = (q >> 6) & 1;
      const int ln  = q & 63;
      const int lr  = ln & 15, lg = ln >> 4;
      const float* src = (mat == 0) ? w1w : (mat == 1) ? w2w : (mat == 2) ? wg1w : wg2w;
      u16x8 tmp;
      if (mat == 0) {
        #pragma unroll
        for (int j = 0; j < 8; ++j)
          tmp[j] = bfu(src[(8 * lg + j) * 32 + lr + 16 * nt]);
      } else {
        #pragma unroll
        for (int j = 0; j < 8; ++j)
          tmp[j] = bfu(src[(4 * lg + (j & 3) + 16 * (j >> 2)) * 32 + lr + 16 * nt]);
      }
      *(u16x8*)(wtg + ((size_t)PHA_FRAG + q) * 8) = tmp;
    }
  }
}

// =====================================================================
// main fused kernel
// =====================================================================
__global__ __launch_bounds__(NTHR, 4) void vsn_main(
    const float* __restrict__ x,
    const unsigned short* __restrict__ wtg,
    const float* __restrict__ vect,
    const float* __restrict__ b1w, const float* __restrict__ b2w,
    const float* __restrict__ bg1w, const float* __restrict__ bg2w,
    const float* __restrict__ gammaw, const float* __restrict__ betaw,
    float* __restrict__ out, float* __restrict__ wout)
{
  __shared__ __align__(16) char smem[SMEM_BYTES];
  const int t  = threadIdx.x;
  const int r0 = blockIdx.x * RPB;

  float* xt  = (float*)(smem + X_OFF);                      // [16][36] f32
  unsigned short* wtlb = (unsigned short*)(smem + WT_OFF);  // [16][40] bf16
  float* vAl = (float*)(smem + VA_OFF);                     // [6][32] f32

  const int wid  = t >> 6;            // wave 0..3 -> f-quarter
  const int lane = t & 63;
  const int lr   = lane & 15;
  const int lg   = lane >> 4;
  const int fbase = wid * 8;

  // ---- stage x tile: 16 rows x 32 f = 128 f4 ----
  if (t < 128) {
    f4 v = ((const f4*)(x + (size_t)r0 * F_DIM))[t];
    *((f4*)(xt + (t >> 3) * 36 + ((t & 7) << 2))) = v;
  }
  // ---- stage phase-A bias vectors ----
  if (t < 48) {
    int m = t >> 3, off = (t & 7) << 2;
    const float* src = (m==0)?b1w:(m==1)?b2w:(m==2)?bg1w:(m==3)?bg2w:(m==4)?gammaw:betaw;
    *(f4*)(vAl + m * 32 + off) = *((const f4*)(src + off));
  }
  __syncthreads();   // the ONLY pre-loop barrier

  // ================= PHASE A : weights GRN + softmax (MFMA, per-wave) ===
  {
    const bf16x8* pf = ((const bf16x8*)wtg) + PHA_FRAG;

    // X^T B-frag: xb[j] = x[row=lr][k=8lg+j]
    f4 xa0 = *(const f4*)(xt + lr * 36 + 8 * lg);
    f4 xa1 = *(const f4*)(xt + lr * 36 + 8 * lg + 4);
    bf16x8 xb;
    #pragma unroll
    for (int j = 0; j < 4; ++j) { xb[j] = (short)bfu(xa0[j]); xb[4 + j] = (short)bfu(xa1[j]); }

    // stage 1: H1^T = W1^T @ X^T ; C: col=lr(row), row=g=4lg+reg+16nt
    f32x4 c1a[2];
    #pragma unroll
    for (int nt = 0; nt < 2; ++nt)
      c1a[nt] = __builtin_amdgcn_mfma_f32_16x16x32_bf16(
          pf[(0 * 2 + nt) * 64 + lane], xb, (f32x4){0.f,0.f,0.f,0.f}, 0, 0, 0);
    float hv[8];
    #pragma unroll
    for (int nt = 0; nt < 2; ++nt)
      #pragma unroll
      for (int rg = 0; rg < 4; ++rg) {
        const int g = 4 * lg + rg + 16 * nt;
        float h = c1a[nt][rg] + vAl[g];
        hv[nt * 4 + rg] = h > 0.f ? h : (__expf(h) - 1.f);
      }
    bf16x8 hf;
    #pragma unroll
    for (int j = 0; j < 8; ++j) hf[j] = (short)bfu(hv[j]);   // j=(nt*4+rg) matches custom k-order

    // stage 2: H2^T = W2^T @ H1^T (custom k-order A-frags)
    f32x4 c2a[2];
    #pragma unroll
    for (int nt = 0; nt < 2; ++nt)
      c2a[nt] = __builtin_amdgcn_mfma_f32_16x16x32_bf16(
          pf[(1 * 2 + nt) * 64 + lane], hf, (f32x4){0.f,0.f,0.f,0.f}, 0, 0, 0);
    bf16x8 h2f;
    #pragma unroll
    for (int nt = 0; nt < 2; ++nt)
      #pragma unroll
      for (int rg = 0; rg < 4; ++rg) {
        const int g = 4 * lg + rg + 16 * nt;
        h2f[nt * 4 + rg] = (short)bfu(c2a[nt][rg] + vAl[32 + g]);
      }

    // stage 3: GLU
    f32x4 cga[2], cgb[2];
    #pragma unroll
    for (int nt = 0; nt < 2; ++nt) {
      cga[nt] = __builtin_amdgcn_mfma_f32_16x16x32_bf16(
          pf[(2 * 2 + nt) * 64 + lane], h2f, (f32x4){0.f,0.f,0.f,0.f}, 0, 0, 0);
      cgb[nt] = __builtin_amdgcn_mfma_f32_16x16x32_bf16(
          pf[(3 * 2 + nt) * 64 + lane], h2f, (f32x4){0.f,0.f,0.f,0.f}, 0, 0, 0);
    }
    float zv[8];
    float s1 = 0.f, s2 = 0.f;
    #pragma unroll
    for (int nt = 0; nt < 2; ++nt)
      #pragma unroll
      for (int rg = 0; rg < 4; ++rg) {
        const int g = 4 * lg + rg + 16 * nt;
        float a = cga[nt][rg] + vAl[64 + g];
        float b = cgb[nt][rg] + vAl[96 + g];
        float sg = __builtin_amdgcn_rcpf(1.f + __expf(-b));
        float z = a * sg + xt[lr * 36 + g];
        zv[nt * 4 + rg] = z;
        s1 += z; s2 += z * z;
      }
    // reduce over the 4 lanes sharing lr (xor 16, 32)
    s1 += __shfl_xor(s1, 16, 64); s1 += __shfl_xor(s1, 32, 64);
    s2 += __shfl_xor(s2, 16, 64); s2 += __shfl_xor(s2, 32, 64);
    const float mA = s1 * 0.03125f;
    const float vA = s2 * 0.03125f - mA * mA;
    const float rsA = __builtin_amdgcn_rsqf(vA + 1e-3f);
    float yv[8], mx = -1e30f;
    #pragma unroll
    for (int nt = 0; nt < 2; ++nt)
      #pragma unroll
      for (int rg = 0; rg < 4; ++rg) {
        const int g = 4 * lg + rg + 16 * nt;
        float y = (zv[nt * 4 + rg] - mA) * rsA * vAl[128 + g] + vAl[160 + g];
        yv[nt * 4 + rg] = y;
        mx = fmaxf(mx, y);
      }
    mx = fmaxf(mx, __shfl_xor(mx, 16, 64));
    mx = fmaxf(mx, __shfl_xor(mx, 32, 64));
    float ev[8], es = 0.f;
    #pragma unroll
    for (int j = 0; j < 8; ++j) { ev[j] = __expf(yv[j] - mx); es += ev[j]; }
    es += __shfl_xor(es, 16, 64); es += __shfl_xor(es, 32, 64);
    const float inv = __builtin_amdgcn_rcpf(es);
    #pragma unroll
    for (int nt = 0; nt < 2; ++nt)
      #pragma unroll
      for (int rg = 0; rg < 4; ++rg) {
        const int g = 4 * lg + rg + 16 * nt;
        wtlb[lr * 40 + g] = bfu(ev[nt * 4 + rg] * inv);   // redundant across waves: benign
      }
    // wout: each wave's own writes are lgkm-ordered; waves 0,1 emit f32 copy
    if (t < 128) {
      const int row = t >> 3, c4 = (t & 7) << 2;
      u16x4 wq = *(const u16x4*)(wtlb + row * 40 + c4);
      f4 wo = { bf2f(wq[0]), bf2f(wq[1]), bf2f(wq[2]), bf2f(wq[3]) };
      *(f4*)(wout + (size_t)(r0 + row) * 32 + c4) = wo;
    }
  }

  // ================= PHASE B : per-feature GRNs (MFMA, barrier-free) ====
  const bf16x8* wf = (const bf16x8*)wtg;

  f32x4 acc[4];
  #pragma unroll
  for (int nt = 0; nt < 4; ++nt) acc[nt] = (f32x4){0.f, 0.f, 0.f, 0.f};

  for (int i = 0; i < 8; ++i) {
    const int f = fbase + i;
    const float* vb = vect + f * 576;

    // ---- GEMM1 A-operand: W2^T fragments (8 coalesced 16B from L2) ----
    const int base0 = (0 * 32 + f) * 512 + lane;
    bf16x8 w2f[8];
    #pragma unroll
    for (int nt = 0; nt < 4; ++nt)
      #pragma unroll
      for (int kt = 0; kt < 2; ++kt)
        w2f[nt * 2 + kt] = wf[base0 + nt * 128 + kt * 64];

    // ---- h1 B-fragments (batch row = lr), rank-1 + ELU; vect direct ----
    const float s_ = xt[lr * 36 + f];
    bf16x8 afr[2];
    #pragma unroll
    for (int kt = 0; kt < 2; ++kt) {
      const int u0 = 8 * lg + 32 * kt;
      f4 wa  = *(const f4*)(vb + u0);
      f4 wb_ = *(const f4*)(vb + u0 + 4);
      f4 ba  = *(const f4*)(vb + 64 + u0);
      f4 bb_ = *(const f4*)(vb + 64 + u0 + 4);
      bf16x8 af;
      #pragma unroll
      for (int j = 0; j < 4; ++j) {
        float h = s_ * wa[j] + ba[j];
        h = h > 0.f ? h : (__expf(h) - 1.f);
        af[j] = (short)bfu(h);
      }
      #pragma unroll
      for (int j = 0; j < 4; ++j) {
        float h = s_ * wb_[j] + bb_[j];
        h = h > 0.f ? h : (__expf(h) - 1.f);
        af[4 + j] = (short)bfu(h);
      }
      afr[kt] = af;
    }

    // ---- transposed GEMM1 ----
    f32x4 c1[4];
    #pragma unroll
    for (int nt = 0; nt < 4; ++nt) {
      c1[nt] = (f32x4){0.f, 0.f, 0.f, 0.f};
      #pragma unroll
      for (int kt = 0; kt < 2; ++kt)
        c1[nt] = __builtin_amdgcn_mfma_f32_16x16x32_bf16(w2f[nt * 2 + kt], afr[kt], c1[nt], 0, 0, 0);
    }

    // ---- a2 in registers ----
    f4 b2q[4];
    #pragma unroll
    for (int kt = 0; kt < 2; ++kt)
      #pragma unroll
      for (int n2 = 0; n2 < 2; ++n2)
        b2q[n2 + 2 * kt] = *(const f4*)(vb + 128 + 4 * lg + 16 * n2 + 32 * kt);
    bf16x8 a2[2];
    #pragma unroll
    for (int kt = 0; kt < 2; ++kt) {
      bf16x8 af;
      #pragma unroll
      for (int j = 0; j < 8; ++j) {
        const int q = (j >> 2) + 2 * kt;
        af[j] = (short)bfu(c1[q][j & 3] + b2q[q][j & 3]);
      }
      a2[kt] = af;
    }

    // ---- GEMM2a ----
    const int base1 = (1 * 32 + f) * 512 + lane;
    bf16x8 bfa[8];
    #pragma unroll
    for (int nt = 0; nt < 4; ++nt)
      #pragma unroll
      for (int kt = 0; kt < 2; ++kt)
        bfa[nt * 2 + kt] = wf[base1 + nt * 128 + kt * 64];
    f32x4 ca[4], cb[4];
    #pragma unroll
    for (int nt = 0; nt < 4; ++nt) {
      ca[nt] = (f32x4){0.f,0.f,0.f,0.f};
      #pragma unroll
      for (int kt = 0; kt < 2; ++kt)
        ca[nt] = __builtin_amdgcn_mfma_f32_16x16x32_bf16(a2[kt], bfa[nt * 2 + kt], ca[nt], 0, 0, 0);
    }

    // ---- GEMM2b ----
    const int base2 = (2 * 32 + f) * 512 + lane;
    bf16x8 bfb[8];
    #pragma unroll
    for (int nt = 0; nt < 4; ++nt)
      #pragma unroll
      for (int kt = 0; kt < 2; ++kt)
        bfb[nt * 2 + kt] = wf[base2 + nt * 128 + kt * 64];
    #pragma unroll
    for (int nt = 0; nt < 4; ++nt) {
      cb[nt] = (f32x4){0.f,0.f,0.f,0.f};
      #pragma unroll
      for (int kt = 0; kt < 2; ++kt)
        cb[nt] = __builtin_amdgcn_mfma_f32_16x16x32_bf16(a2[kt], bfb[nt * 2 + kt], cb[nt], 0, 0, 0);
    }

    // ---- epilogue: GLU + residual + LN + weighted accumulate ----
    float xr[4], wr[4];
    #pragma unroll
    for (int rg = 0; rg < 4; ++rg) {
      const int rl = 4 * lg + rg;
      xr[rg] = xt[rl * 36 + f];
      wr[rg] = bf2f(wtlb[rl * 40 + f]);
    }
    float zf[4][4];
    float s1[4] = {0.f,0.f,0.f,0.f}, s2[4] = {0.f,0.f,0.f,0.f};
    #pragma unroll
    for (int nt = 0; nt < 4; ++nt) {
      const int u = lr + 16 * nt;
      f4 Q = *(const f4*)(vb + 192 + u * 4);   // bg1, bg2, Wp, bp
      #pragma unroll
      for (int rg = 0; rg < 4; ++rg) {
        float a = ca[nt][rg] + Q[0];
        float b = cb[nt][rg] + Q[1];
        float sg = __builtin_amdgcn_rcpf(1.f + __expf(-b));
        float z = a * sg + (xr[rg] * Q[2] + Q[3]);
        zf[nt][rg] = z;
        s1[rg] += z;
        s2[rg] += z * z;
      }
    }
    #pragma unroll
    for (int rg = 0; rg < 4; ++rg) {
      #pragma unroll
      for (int m = 1; m < 16; m <<= 1) {
        s1[rg] += __shfl_xor(s1[rg], m, 64);
        s2[rg] += __shfl_xor(s2[rg], m, 64);
      }
    }
    float rswr[4], nc2[4];
    #pragma unroll
    for (int rg = 0; rg < 4; ++rg) {
      float mn = s1[rg] * 0.015625f;
      float var = s2[rg] * 0.015625f - mn * mn;
      float rs = __builtin_amdgcn_rsqf(var + 1e-3f);
      rswr[rg] = rs * wr[rg];
      nc2[rg]  = -mn * rswr[rg];
    }
    #pragma unroll
    for (int nt = 0; nt < 4; ++nt) {
      const int u = lr + 16 * nt;
      f2 G = *(const f2*)(vb + 448 + u * 2);   // gamma, beta
      #pragma unroll
      for (int rg = 0; rg < 4; ++rg) {
        float tm = rswr[rg] * zf[nt][rg] + nc2[rg];
        acc[nt][rg] += G.x * tm + G.y * wr[rg];
      }
    }
  }

  // ---- combine the 4 f-quarters and store ----
  __syncthreads();    // xt/wtlb reads done; whole smem free for cmb
  float* cmb = (float*)smem;
  #pragma unroll
  for (int nt = 0; nt < 4; ++nt)
    #pragma unroll
    for (int rg = 0; rg < 4; ++rg)
      cmb[wid * 1024 + (4 * lg + rg) * 64 + lr + 16 * nt] = acc[nt][rg];
  __syncthreads();
  {
    const f4* cmb4 = (const f4*)cmb;
    f4 o = cmb4[t] + cmb4[256 + t] + cmb4[512 + t] + cmb4[768 + t];
    ((f4*)(out + (size_t)r0 * U_DIM))[t] = o;
  }
}

// =====================================================================
extern "C" void kernel_launch(void* const* d_in, const int* in_sizes, int n_in,
                              void* d_out, int out_size, void* d_ws, size_t ws_size,
                              hipStream_t stream)
{
  (void)in_sizes; (void)n_in; (void)out_size; (void)ws_size;
  const float* x    = (const float*)d_in[0];
  const float* W1   = (const float*)d_in[1];
  const float* b1   = (const float*)d_in[2];
  const float* W2   = (const float*)d_in[3];
  const float* b2   = (const float*)d_in[4];
  const float* Wg1  = (const float*)d_in[5];
  const float* bg1  = (const float*)d_in[6];
  const float* Wg2  = (const float*)d_in[7];
  const float* bg2  = (const float*)d_in[8];
  const float* Wp   = (const float*)d_in[9];
  const float* bp   = (const float*)d_in[10];
  const float* gm   = (const float*)d_in[11];
  const float* bt   = (const float*)d_in[12];
  const float* w1w  = (const float*)d_in[13];
  const float* b1w  = (const float*)d_in[14];
  const float* w2w  = (const float*)d_in[15];
  const float* b2w  = (const float*)d_in[16];
  const float* wg1w = (const float*)d_in[17];
  const float* bg1w = (const float*)d_in[18];
  const float* wg2w = (const float*)d_in[19];
  const float* bg2w = (const float*)d_in[20];
  const float* gmw  = (const float*)d_in[21];
  const float* btw  = (const float*)d_in[22];

  unsigned short* wtg = (unsigned short*)d_ws;             // 786432 + 8192 B
  float* vect = (float*)((char*)d_ws + VECT_BYTE_OFF);     // 73728 B

  float* out  = (float*)d_out;
  float* wout = out + (size_t)N_ROWS * U_DIM;

  vsn_prep<<<195, 256, 0, stream>>>(W2, Wg1, Wg2, W1, b1, b2, bg1, bg2, Wp, bp, gm, bt,
                                    w1w, w2w, wg1w, wg2w, wtg, vect);
  vsn_main<<<NBLK, NTHR, 0, stream>>>(x, wtg, vect,
                                      b1w, b2w, bg1w, bg2w, gmw, btw, out, wout);
}

// Round 8
// 178.537 us; speedup vs baseline: 1.2024x; 1.2024x over previous
//
#include <hip/hip_runtime.h>
#include <hip/hip_bf16.h>

// VariableSelectionNetwork (TFT VSN) fused kernel for MI355X / gfx950.
// B=64 T=512 F=32 U=64, rows N = B*T = 32768.
// out = concat( out[N][64], w[N][32] ) in f32.
//
// R7: R5's wave-private LDS vect staging (109us mechanism) + R6's MFMA phase A
// + bias-fold into MFMA C-input + TRANSPOSED GEMM2 (thread holds 16 u of ONE
// row -> LN reduce = 4 shuffle ops) + exp2-prefolded sigmoid (Wg2,bg2 scaled
// by -log2e in prep).

typedef float f4      __attribute__((ext_vector_type(4)));
typedef float f32x4   __attribute__((ext_vector_type(4)));
typedef short bf16x8  __attribute__((ext_vector_type(8)));
typedef unsigned short u16x4 __attribute__((ext_vector_type(4)));
typedef unsigned short u16x8 __attribute__((ext_vector_type(8)));

#define N_ROWS 32768
#define F_DIM  32
#define U_DIM  64
#define RPB    16
#define NTHR   256
#define NBLK   (N_ROWS / RPB)   // 2048
#define LOG2E  1.4426950408889634f

// ws layout: wtg frags [3*32*512 + 512] bf16x8 ; vect at byte 794624
#define PHA_FRAG 49152
#define VECT_BYTE_OFF 794624

// ---- LDS layout (total 17408 B; cmb finale needs 4*1088 f32) ----
#define X_OFF   0        // f32[16][36] x tile                      (2304)
#define WT_OFF  2304     // u16[16][40] softmax weights bf16        (1280)
#define VA_OFF  3584     // f32[6][32]  phase-A bias vectors        (768)
#define VST_OFF 4352     // f32[4][576] wave-private vect stage     (9216)
#define SMEM_BYTES 17408

__device__ __forceinline__ unsigned short bfu(float x) {
  union { __hip_bfloat16 h; unsigned short u; } c;
  c.h = __float2bfloat16(x);
  return c.u;
}
__device__ __forceinline__ float bf2f(unsigned short u) {
  union { float f; unsigned v; } c; c.v = ((unsigned)u) << 16; return c.f;
}

// =====================================================================
// prep:
//  m=0: W2 A-frags for transposed GEMM1 (k = 8g+32kt+j)
//  m=1: Wg1 frags, custom k-order k = 4g+(j&3)+16(j>>2)+32kt
//  m=2: Wg2 frags, same k-order, SCALED by -log2e (exp2 sigmoid)
//  pha: w1w^T (k=8lg+j); w2w/wg1w/wg2w^T custom k-order; wg2w scaled
//  vect[f][576] = [W1|b1|b2|bg1|bg2*(-log2e)|Wp|bp|gamma|beta], each [64]
// =====================================================================
__global__ __launch_bounds__(256) void vsn_prep(
    const float* __restrict__ W2,  const float* __restrict__ Wg1, const float* __restrict__ Wg2,
    const float* __restrict__ W1,  const float* __restrict__ b1,  const float* __restrict__ b2,
    const float* __restrict__ bg1, const float* __restrict__ bg2,
    const float* __restrict__ Wp,  const float* __restrict__ bp,
    const float* __restrict__ gamma_, const float* __restrict__ beta_,
    const float* __restrict__ w1w, const float* __restrict__ w2w,
    const float* __restrict__ wg1w, const float* __restrict__ wg2w,
    unsigned short* __restrict__ wtg, float* __restrict__ vect)
{
  const int t = threadIdx.x, blk = blockIdx.x;
  if (blk < 192) {
    const int m = blk >> 6;              // 0..2
    const int f = (blk >> 1) & 31;
    const int half = blk & 1;
    const float* src = (m == 0) ? W2 : (m == 1) ? Wg1 : Wg2;
    src += f * 4096;
    const float sc = (m == 2) ? -LOG2E : 1.0f;
    const int c  = half * 256 + t;       // chunk 0..511
    const int nt = c >> 7;
    const int rr = c & 127;
    const int kt = rr >> 6;
    const int ln = rr & 63;
    const int g  = ln >> 4, lrr = ln & 15;
    const int uo = lrr + 16 * nt;
    u16x8 tmp;
    if (m == 0) {
      #pragma unroll
      for (int j = 0; j < 8; ++j)
        tmp[j] = bfu(src[(8 * g + 32 * kt + j) * 64 + uo]);
    } else {
      #pragma unroll
      for (int j = 0; j < 8; ++j)
        tmp[j] = bfu(src[(4 * g + (j & 3) + 16 * (j >> 2) + 32 * kt) * 64 + uo] * sc);
    }
    *(u16x8*)(wtg + ((size_t)(m * 32 + f) * 512 + c) * 8) = tmp;
  } else if (blk < 194) {
    const int h = blk - 192;             // 0..1
    for (int i = h * 1024 + t; i < (h + 1) * 1024; i += 256) {
      const int f = i >> 6, u = i & 63;
      float* vf = vect + f * 576;
      vf[u]       = W1[i];
      vf[64 + u]  = b1[i];
      vf[128 + u] = b2[i];
      vf[192 + u] = bg1[i];
      vf[256 + u] = bg2[i] * (-LOG2E);
      vf[320 + u] = Wp[i];
      vf[384 + u] = bp[i];
      vf[448 + u] = gamma_[i];
      vf[512 + u] = beta_[i];
    }
  } else {
    // phase-A weight frags: 512 frags
    #pragma unroll
    for (int cc = 0; cc < 2; ++cc) {
      const int q = t + cc * 256;        // 0..511
      const int mat = q >> 7;            // 0 w1w, 1 w2w, 2 wg1w, 3 wg2w
      const int nt  = (q >> 6) & 1;
      const int ln  = q & 63;
      const int lr  = ln & 15, lg = ln >> 4;
      const float* src = (mat == 0) ? w1w : (mat == 1) ? w2w : (mat == 2) ? wg1w : wg2w;
      const float sc = (mat == 3) ? -LOG2E : 1.0f;
      u16x8 tmp;
      if (mat == 0) {
        #pragma unroll
        for (int j = 0; j < 8; ++j)
          tmp[j] = bfu(src[(8 * lg + j) * 32 + lr + 16 * nt]);
      } else {
        #pragma unroll
        for (int j = 0; j < 8; ++j)
          tmp[j] = bfu(src[(4 * lg + (j & 3) + 16 * (j >> 2)) * 32 + lr + 16 * nt] * sc);
      }
      *(u16x8*)(wtg + ((size_t)PHA_FRAG + q) * 8) = tmp;
    }
  }
}

// =====================================================================
// main fused kernel
// =====================================================================
__global__ __launch_bounds__(NTHR, 4) void vsn_main(
    const float* __restrict__ x,
    const unsigned short* __restrict__ wtg,
    const float* __restrict__ vect,
    const float* __restrict__ b1w, const float* __restrict__ b2w,
    const float* __restrict__ bg1w, const float* __restrict__ bg2w,
    const float* __restrict__ gammaw, const float* __restrict__ betaw,
    float* __restrict__ out, float* __restrict__ wout)
{
  __shared__ __align__(16) char smem[SMEM_BYTES];
  const int t  = threadIdx.x;
  const int r0 = blockIdx.x * RPB;

  float* xt  = (float*)(smem + X_OFF);                      // [16][36] f32
  unsigned short* wtlb = (unsigned short*)(smem + WT_OFF);  // [16][40] bf16
  float* vAl = (float*)(smem + VA_OFF);                     // [6][32] f32
  float* vstf = (float*)(smem + VST_OFF);                   // [4][576] f32

  const int wid  = t >> 6;            // wave 0..3 -> f-quarter
  const int lane = t & 63;
  const int lr   = lane & 15;
  const int lg   = lane >> 4;
  const int fbase = wid * 8;

  // ---- stage x tile: 16 rows x 32 f = 128 f4 ----
  if (t < 128) {
    f4 v = ((const f4*)(x + (size_t)r0 * F_DIM))[t];
    *((f4*)(xt + (t >> 3) * 36 + ((t & 7) << 2))) = v;
  }
  // ---- stage phase-A bias vectors (bg2w scaled for exp2 sigmoid) ----
  if (t < 48) {
    int m = t >> 3, off = (t & 7) << 2;
    const float* src = (m==0)?b1w:(m==1)?b2w:(m==2)?bg1w:(m==3)?bg2w:(m==4)?gammaw:betaw;
    f4 v = *((const f4*)(src + off));
    if (m == 3) { v[0]*=-LOG2E; v[1]*=-LOG2E; v[2]*=-LOG2E; v[3]*=-LOG2E; }
    *(f4*)(vAl + m * 32 + off) = v;
  }

  // ---- prefetch f=fbase vect into regs ----
  const f4* vect4 = (const f4*)vect;
  f4 rv0 = vect4[fbase * 144 + lane];
  f4 rv1 = vect4[fbase * 144 + 64 + lane];
  f4 rv2 = {};
  if (lane < 16) rv2 = vect4[fbase * 144 + 128 + lane];

  __syncthreads();   // the ONLY pre-loop barrier

  // ---- write f=fbase vect to wave-private LDS (in-order DS, no barrier) ----
  f4* vst4 = ((f4*)vstf) + wid * 144;
  float* vsc = vstf + wid * 576;
  vst4[lane] = rv0; vst4[64 + lane] = rv1;
  if (lane < 16) vst4[128 + lane] = rv2;

  // ================= PHASE A : weights GRN + softmax (MFMA, per-wave) ===
  {
    const bf16x8* pf = ((const bf16x8*)wtg) + PHA_FRAG;

    f4 xa0 = *(const f4*)(xt + lr * 36 + 8 * lg);
    f4 xa1 = *(const f4*)(xt + lr * 36 + 8 * lg + 4);
    bf16x8 xb;
    #pragma unroll
    for (int j = 0; j < 4; ++j) { xb[j] = (short)bfu(xa0[j]); xb[4 + j] = (short)bfu(xa1[j]); }

    // stage 1: H1^T = W1^T @ X^T + b1w (C-init)
    f32x4 c1a[2];
    #pragma unroll
    for (int nt = 0; nt < 2; ++nt)
      c1a[nt] = __builtin_amdgcn_mfma_f32_16x16x32_bf16(
          pf[(0 * 2 + nt) * 64 + lane], xb,
          *(const f32x4*)(vAl + 4 * lg + 16 * nt), 0, 0, 0);
    bf16x8 hf;
    #pragma unroll
    for (int nt = 0; nt < 2; ++nt)
      #pragma unroll
      for (int rg = 0; rg < 4; ++rg) {
        float h = c1a[nt][rg];
        hf[nt * 4 + rg] = (short)bfu(h > 0.f ? h : (__expf(h) - 1.f));
      }

    // stage 2: H2^T = W2^T @ H1^T + b2w
    f32x4 c2a[2];
    #pragma unroll
    for (int nt = 0; nt < 2; ++nt)
      c2a[nt] = __builtin_amdgcn_mfma_f32_16x16x32_bf16(
          pf[(1 * 2 + nt) * 64 + lane], hf,
          *(const f32x4*)(vAl + 32 + 4 * lg + 16 * nt), 0, 0, 0);
    bf16x8 h2f;
    #pragma unroll
    for (int nt = 0; nt < 2; ++nt)
      #pragma unroll
      for (int rg = 0; rg < 4; ++rg)
        h2f[nt * 4 + rg] = (short)bfu(c2a[nt][rg]);

    // stage 3: GLU (gate weights pre-scaled by -log2e)
    f32x4 cga[2], cgb[2];
    #pragma unroll
    for (int nt = 0; nt < 2; ++nt) {
      cga[nt] = __builtin_amdgcn_mfma_f32_16x16x32_bf16(
          pf[(2 * 2 + nt) * 64 + lane], h2f,
          *(const f32x4*)(vAl + 64 + 4 * lg + 16 * nt), 0, 0, 0);
      cgb[nt] = __builtin_amdgcn_mfma_f32_16x16x32_bf16(
          pf[(3 * 2 + nt) * 64 + lane], h2f,
          *(const f32x4*)(vAl + 96 + 4 * lg + 16 * nt), 0, 0, 0);
    }
    float zv[8];
    float s1 = 0.f, s2 = 0.f;
    #pragma unroll
    for (int nt = 0; nt < 2; ++nt)
      #pragma unroll
      for (int rg = 0; rg < 4; ++rg) {
        const int g = 4 * lg + rg + 16 * nt;
        float sg = __builtin_amdgcn_rcpf(1.f + __builtin_amdgcn_exp2f(cgb[nt][rg]));
        float z = cga[nt][rg] * sg + xt[lr * 36 + g];
        zv[nt * 4 + rg] = z;
        s1 += z; s2 += z * z;
      }
    s1 += __shfl_xor(s1, 16, 64); s1 += __shfl_xor(s1, 32, 64);
    s2 += __shfl_xor(s2, 16, 64); s2 += __shfl_xor(s2, 32, 64);
    const float mA = s1 * 0.03125f;
    const float vA = s2 * 0.03125f - mA * mA;
    const float rsA = __builtin_amdgcn_rsqf(vA + 1e-3f);
    float yv[8], mx = -1e30f;
    #pragma unroll
    for (int nt = 0; nt < 2; ++nt)
      #pragma unroll
      for (int rg = 0; rg < 4; ++rg) {
        const int g = 4 * lg + rg + 16 * nt;
        float y = (zv[nt * 4 + rg] - mA) * rsA * vAl[128 + g] + vAl[160 + g];
        yv[nt * 4 + rg] = y;
        mx = fmaxf(mx, y);
      }
    mx = fmaxf(mx, __shfl_xor(mx, 16, 64));
    mx = fmaxf(mx, __shfl_xor(mx, 32, 64));
    float ev[8], es = 0.f;
    #pragma unroll
    for (int j = 0; j < 8; ++j) { ev[j] = __expf(yv[j] - mx); es += ev[j]; }
    es += __shfl_xor(es, 16, 64); es += __shfl_xor(es, 32, 64);
    const float inv = __builtin_amdgcn_rcpf(es);
    #pragma unroll
    for (int nt = 0; nt < 2; ++nt)
      #pragma unroll
      for (int rg = 0; rg < 4; ++rg) {
        const int g = 4 * lg + rg + 16 * nt;
        wtlb[lr * 40 + g] = bfu(ev[nt * 4 + rg] * inv);
      }
    if (t < 128) {
      const int row = t >> 3, c4 = (t & 7) << 2;
      u16x4 wq = *(const u16x4*)(wtlb + row * 40 + c4);
      f4 wo = { bf2f(wq[0]), bf2f(wq[1]), bf2f(wq[2]), bf2f(wq[3]) };
      *(f4*)(wout + (size_t)(r0 + row) * 32 + c4) = wo;
    }
  }

  // ================= PHASE B : per-feature GRNs (MFMA, barrier-free) ====
  const bf16x8* wf = (const bf16x8*)wtg;

  f32x4 acc[4];
  #pragma unroll
  for (int nt = 0; nt < 4; ++nt) acc[nt] = (f32x4){0.f, 0.f, 0.f, 0.f};

  for (int i = 0; i < 8; ++i) {
    const int f = fbase + i;

    // ---- GEMM1 A-operand: W2^T fragments ----
    const int base0 = (0 * 32 + f) * 512 + lane;
    bf16x8 w2f[8];
    #pragma unroll
    for (int nt = 0; nt < 4; ++nt)
      #pragma unroll
      for (int kt = 0; kt < 2; ++kt)
        w2f[nt * 2 + kt] = wf[base0 + nt * 128 + kt * 64];

    // ---- h1 B-fragments (batch col = lr), rank-1 + ELU ----
    const float s_ = xt[lr * 36 + f];
    bf16x8 afr[2];
    #pragma unroll
    for (int kt = 0; kt < 2; ++kt) {
      const int u0 = 8 * lg + 32 * kt;
      f4 wa  = *(const f4*)(vsc + u0);
      f4 wb_ = *(const f4*)(vsc + u0 + 4);
      f4 ba  = *(const f4*)(vsc + 64 + u0);
      f4 bb_ = *(const f4*)(vsc + 64 + u0 + 4);
      bf16x8 af;
      #pragma unroll
      for (int j = 0; j < 4; ++j) {
        float h = s_ * wa[j] + ba[j];
        h = h > 0.f ? h : (__expf(h) - 1.f);
        af[j] = (short)bfu(h);
      }
      #pragma unroll
      for (int j = 0; j < 4; ++j) {
        float h = s_ * wb_[j] + bb_[j];
        h = h > 0.f ? h : (__expf(h) - 1.f);
        af[4 + j] = (short)bfu(h);
      }
      afr[kt] = af;
    }

    // ---- transposed GEMM1: c1 = H2^T, C-init = b2 ----
    f32x4 c1[4];
    #pragma unroll
    for (int nt = 0; nt < 4; ++nt) {
      c1[nt] = *(const f32x4*)(vsc + 128 + 4 * lg + 16 * nt);
      #pragma unroll
      for (int kt = 0; kt < 2; ++kt)
        c1[nt] = __builtin_amdgcn_mfma_f32_16x16x32_bf16(w2f[nt * 2 + kt], afr[kt], c1[nt], 0, 0, 0);
    }

    // ---- a2 (h2^T as B-frag, custom k-order) ----
    bf16x8 a2[2];
    #pragma unroll
    for (int kt = 0; kt < 2; ++kt) {
      bf16x8 af;
      #pragma unroll
      for (int j = 0; j < 8; ++j)
        af[j] = (short)bfu(c1[(j >> 2) + 2 * kt][j & 3]);
      a2[kt] = af;
    }

    // ---- transposed GEMM2a: ca = (H2@Wg1)^T + bg1 (C-init) ----
    const int base1 = (1 * 32 + f) * 512 + lane;
    bf16x8 bfa[8];
    #pragma unroll
    for (int nt = 0; nt < 4; ++nt)
      #pragma unroll
      for (int kt = 0; kt < 2; ++kt)
        bfa[nt * 2 + kt] = wf[base1 + nt * 128 + kt * 64];
    f32x4 ca[4], cb[4];
    #pragma unroll
    for (int nt = 0; nt < 4; ++nt) {
      ca[nt] = *(const f32x4*)(vsc + 192 + 16 * nt + 4 * lg);
      #pragma unroll
      for (int kt = 0; kt < 2; ++kt)
        ca[nt] = __builtin_amdgcn_mfma_f32_16x16x32_bf16(bfa[nt * 2 + kt], a2[kt], ca[nt], 0, 0, 0);
    }

    // ---- transposed GEMM2b (Wg2 pre-scaled by -log2e) ----
    const int base2 = (2 * 32 + f) * 512 + lane;
    bf16x8 bfb[8];
    #pragma unroll
    for (int nt = 0; nt < 4; ++nt)
      #pragma unroll
      for (int kt = 0; kt < 2; ++kt)
        bfb[nt * 2 + kt] = wf[base2 + nt * 128 + kt * 64];
    #pragma unroll
    for (int nt = 0; nt < 4; ++nt) {
      cb[nt] = *(const f32x4*)(vsc + 256 + 16 * nt + 4 * lg);
      #pragma unroll
      for (int kt = 0; kt < 2; ++kt)
        cb[nt] = __builtin_amdgcn_mfma_f32_16x16x32_bf16(bfb[nt * 2 + kt], a2[kt], cb[nt], 0, 0, 0);
    }

    // ---- prefetch vect f+1 ----
    if (i < 7) {
      rv0 = vect4[(f + 1) * 144 + lane];
      rv1 = vect4[(f + 1) * 144 + 64 + lane];
      if (lane < 16) rv2 = vect4[(f + 1) * 144 + 128 + lane];
    }

    // ---- epilogue (transposed): thread owns row lr, u = 16nt+4lg+rg ----
    const float wr_ = bf2f(wtlb[lr * 40 + f]);
    float zf[4][4];
    float s1 = 0.f, s2 = 0.f;
    #pragma unroll
    for (int nt = 0; nt < 4; ++nt) {
      f4 wp4 = *(const f4*)(vsc + 320 + 16 * nt + 4 * lg);
      f4 bp4 = *(const f4*)(vsc + 384 + 16 * nt + 4 * lg);
      #pragma unroll
      for (int rg = 0; rg < 4; ++rg) {
        float sg = __builtin_amdgcn_rcpf(1.f + __builtin_amdgcn_exp2f(cb[nt][rg]));
        float z = ca[nt][rg] * sg + (s_ * wp4[rg] + bp4[rg]);
        zf[nt][rg] = z;
        s1 += z;
        s2 += z * z;
      }
    }
    s1 += __shfl_xor(s1, 16, 64); s1 += __shfl_xor(s1, 32, 64);
    s2 += __shfl_xor(s2, 16, 64); s2 += __shfl_xor(s2, 32, 64);
    const float mn = s1 * 0.015625f;
    const float var = s2 * 0.015625f - mn * mn;
    const float rs = __builtin_amdgcn_rsqf(var + 1e-3f);
    const float rswr = rs * wr_;
    const float nc2 = -mn * rswr;
    #pragma unroll
    for (int nt = 0; nt < 4; ++nt) {
      f4 g4 = *(const f4*)(vsc + 448 + 16 * nt + 4 * lg);
      f4 b4 = *(const f4*)(vsc + 512 + 16 * nt + 4 * lg);
      #pragma unroll
      for (int rg = 0; rg < 4; ++rg)
        acc[nt][rg] += g4[rg] * (rswr * zf[nt][rg] + nc2) + b4[rg] * wr_;
    }

    // ---- write f+1 vect to wave-private LDS (after all vsc reads) ----
    if (i < 7) {
      vst4[lane] = rv0; vst4[64 + lane] = rv1;
      if (lane < 16) vst4[128 + lane] = rv2;
    }
  }

  // ---- combine the 4 f-quarters (padded cmb, stride 68) and store ----
  __syncthreads();
  float* cmb = (float*)smem;
  #pragma unroll
  for (int nt = 0; nt < 4; ++nt)
    *(f4*)(cmb + wid * 1088 + lr * 68 + 16 * nt + 4 * lg) = acc[nt];
  __syncthreads();
  {
    const int row = t >> 4, u4 = (t & 15) << 2;
    const float* cp = cmb + row * 68 + u4;
    f4 o = *(const f4*)(cp) + *(const f4*)(cp + 1088) +
           *(const f4*)(cp + 2176) + *(const f4*)(cp + 3264);
    *(f4*)(out + (size_t)(r0 + row) * U_DIM + u4) = o;
  }
}

// =====================================================================
extern "C" void kernel_launch(void* const* d_in, const int* in_sizes, int n_in,
                              void* d_out, int out_size, void* d_ws, size_t ws_size,
                              hipStream_t stream)
{
  (void)in_sizes; (void)n_in; (void)out_size; (void)ws_size;
  const float* x    = (const float*)d_in[0];
  const float* W1   = (const float*)d_in[1];
  const float* b1   = (const float*)d_in[2];
  const float* W2   = (const float*)d_in[3];
  const float* b2   = (const float*)d_in[4];
  const float* Wg1  = (const float*)d_in[5];
  const float* bg1  = (const float*)d_in[6];
  const float* Wg2  = (const float*)d_in[7];
  const float* bg2  = (const float*)d_in[8];
  const float* Wp   = (const float*)d_in[9];
  const float* bp   = (const float*)d_in[10];
  const float* gm   = (const float*)d_in[11];
  const float* bt   = (const float*)d_in[12];
  const float* w1w  = (const float*)d_in[13];
  const float* b1w  = (const float*)d_in[14];
  const float* w2w  = (const float*)d_in[15];
  const float* b2w  = (const float*)d_in[16];
  const float* wg1w = (const float*)d_in[17];
  const float* bg1w = (const float*)d_in[18];
  const float* wg2w = (const float*)d_in[19];
  const float* bg2w = (const float*)d_in[20];
  const float* gmw  = (const float*)d_in[21];
  const float* btw  = (const float*)d_in[22];

  unsigned short* wtg = (unsigned short*)d_ws;             // 786432 + 8192 B
  float* vect = (float*)((char*)d_ws + VECT_BYTE_OFF);     // 73728 B

  float* out  = (float*)d_out;
  float* wout = out + (size_t)N_ROWS * U_DIM;

  vsn_prep<<<195, 256, 0, stream>>>(W2, Wg1, Wg2, W1, b1, b2, bg1, bg2, Wp, bp, gm, bt,
                                    w1w, w2w, wg1w, wg2w, wtg, vect);
  vsn_main<<<NBLK, NTHR, 0, stream>>>(x, wtg, vect,
                                      b1w, b2w, bg1w, bg2w, gmw, btw, out, wout);
}